// Round 1
// baseline (268.644 us; speedup 1.0000x reference)
//
#include <hip/hip_runtime.h>

#define N_ITER 100

// DPP move helper: ctrl must be compile-time constant.
template <int CTRL>
__device__ __forceinline__ float dpp_mov_f32(float x) {
  int r = __builtin_amdgcn_update_dpp(0, __float_as_int(x), CTRL, 0xF, 0xF, true);
  return __int_as_float(r);
}

// Full sum across a 16-lane DPP row via rotations (all lanes end with total).
__device__ __forceinline__ float row16_sum(float s) {
  s += dpp_mov_f32<0x128>(s);  // row_ror:8
  s += dpp_mov_f32<0x124>(s);  // row_ror:4
  s += dpp_mov_f32<0x122>(s);  // row_ror:2
  s += dpp_mov_f32<0x121>(s);  // row_ror:1
  return s;
}

// One block per matrix. Thread (tx=tid&15, ty=tid>>4) owns rows [4*ty,4*ty+4),
// cols [16*tx, 16*tx+16). Rows live within one 16-lane DPP row (lane = tx + 16*(ty&3)).
__global__ __launch_bounds__(1024) void sinkhorn16(const float* __restrict__ alpha,
                                                   float* __restrict__ out) {
  constexpr int SSTR = 264;  // padded slot stride (floats) to spread banks
  __shared__ float colpart[32 * SSTR];
  __shared__ float colrcp[256];

  const int tid  = threadIdx.x;
  const int tx   = tid & 15;
  const int ty   = tid >> 4;
  const int lane = tid & 63;
  const int wave = tid >> 6;

  const size_t mbase = (size_t)blockIdx.x * (256 * 256);
  const float* A = alpha + mbase;
  float*       O = out + mbase;

  float v[4][16];

  // Load + exp(alpha/TAU). 1/0.1f rounds exactly to 10.0f in fp32.
#pragma unroll
  for (int i = 0; i < 4; ++i) {
    const float4* src = (const float4*)(A + (ty * 4 + i) * 256 + tx * 16);
#pragma unroll
    for (int k = 0; k < 4; ++k) {
      float4 x = src[k];
      v[i][4 * k + 0] = __expf(x.x * 10.0f);
      v[i][4 * k + 1] = __expf(x.y * 10.0f);
      v[i][4 * k + 2] = __expf(x.z * 10.0f);
      v[i][4 * k + 3] = __expf(x.w * 10.0f);
    }
  }

  for (int it = 0; it < N_ITER; ++it) {
    // ---------------- row normalize (no DS ops) ----------------
#pragma unroll
    for (int i = 0; i < 4; ++i) {
      float t0 = (v[i][0] + v[i][8])  + (v[i][4] + v[i][12]);
      float t1 = (v[i][1] + v[i][9])  + (v[i][5] + v[i][13]);
      float t2 = (v[i][2] + v[i][10]) + (v[i][6] + v[i][14]);
      float t3 = (v[i][3] + v[i][11]) + (v[i][7] + v[i][15]);
      float s  = (t0 + t1) + (t2 + t3);
      s = row16_sum(s);                       // sum over the 16 tx threads
      float r = __builtin_amdgcn_rcpf(s);
#pragma unroll
      for (int j = 0; j < 16; ++j) v[i][j] *= r;
    }

    // ---------------- col normalize ----------------
    float p[16];
#pragma unroll
    for (int j = 0; j < 16; ++j) p[j] = (v[0][j] + v[1][j]) + (v[2][j] + v[3][j]);
    // combine delta pairs (ty&3: 0<->1, 2<->3)
#pragma unroll
    for (int j = 0; j < 16; ++j) p[j] += __shfl_xor(p[j], 16);

    const int dq = lane >> 4;  // = ty & 3
    if ((dq & 1) == 0) {       // lanes with delta 0 and 2 hold pair sums
      const int slot = wave * 2 + (dq >> 1);   // 32 slots of partial col sums
      float* dst = &colpart[slot * SSTR + tx * 16];
#pragma unroll
      for (int k = 0; k < 4; ++k)
        *((float4*)(dst + 4 * k)) =
            make_float4(p[4 * k], p[4 * k + 1], p[4 * k + 2], p[4 * k + 3]);
    }
    __syncthreads();

    if (tid < 256) {  // one thread per column: sum 32 partials, reciprocal
      float a0 = colpart[0 * SSTR + tid];
      float a1 = colpart[1 * SSTR + tid];
      float a2 = colpart[2 * SSTR + tid];
      float a3 = colpart[3 * SSTR + tid];
#pragma unroll
      for (int w = 4; w < 32; w += 4) {
        a0 += colpart[(w + 0) * SSTR + tid];
        a1 += colpart[(w + 1) * SSTR + tid];
        a2 += colpart[(w + 2) * SSTR + tid];
        a3 += colpart[(w + 3) * SSTR + tid];
      }
      colrcp[tid] = __builtin_amdgcn_rcpf((a0 + a1) + (a2 + a3));
    }
    __syncthreads();

#pragma unroll
    for (int k = 0; k < 4; ++k) {
      float4 rc = *((const float4*)(&colrcp[tx * 16 + 4 * k]));
#pragma unroll
      for (int i = 0; i < 4; ++i) {
        v[i][4 * k + 0] *= rc.x;
        v[i][4 * k + 1] *= rc.y;
        v[i][4 * k + 2] *= rc.z;
        v[i][4 * k + 3] *= rc.w;
      }
    }
  }

  // Store: v is already exp(log_alpha_final).
#pragma unroll
  for (int i = 0; i < 4; ++i) {
    float4* dst = (float4*)(O + (ty * 4 + i) * 256 + tx * 16);
#pragma unroll
    for (int k = 0; k < 4; ++k)
      dst[k] = make_float4(v[i][4 * k], v[i][4 * k + 1], v[i][4 * k + 2], v[i][4 * k + 3]);
  }
}

extern "C" void kernel_launch(void* const* d_in, const int* in_sizes, int n_in,
                              void* d_out, int out_size, void* d_ws, size_t ws_size,
                              hipStream_t stream) {
  const float* alpha = (const float*)d_in[0];
  float* out = (float*)d_out;
  sinkhorn16<<<dim3(16), dim3(1024), 0, stream>>>(alpha, out);
}

// Round 2
// 245.632 us; speedup vs baseline: 1.0937x; 1.0937x over previous
//
#include <hip/hip_runtime.h>

#define N_ITER 100

// DPP move helper: ctrl must be compile-time constant.
template <int CTRL>
__device__ __forceinline__ float dpp_mov_f32(float x) {
  int r = __builtin_amdgcn_update_dpp(0, __float_as_int(x), CTRL, 0xF, 0xF, true);
  return __int_as_float(r);
}

// Full sum across a 16-lane DPP row via rotations (all lanes end with total).
__device__ __forceinline__ float row16_sum(float s) {
  s += dpp_mov_f32<0x128>(s);  // row_ror:8
  s += dpp_mov_f32<0x124>(s);  // row_ror:4
  s += dpp_mov_f32<0x122>(s);  // row_ror:2
  s += dpp_mov_f32<0x121>(s);  // row_ror:1
  return s;
}

// Sum across the 4 16-lane rows of a wave (lane ^16 and ^32), result in all lanes.
__device__ __forceinline__ float dq4_sum(float x) {
#if defined(__has_builtin)
#if __has_builtin(__builtin_amdgcn_permlane16_swap) && __has_builtin(__builtin_amdgcn_permlane32_swap)
  {
    // VALU cross-lane (gfx950): swap paired 16-rows / 32-halves between two
    // regs; with both inputs equal, sum of the two results = pairwise row sum.
    typedef unsigned u2 __attribute__((ext_vector_type(2)));
    unsigned xi = __float_as_uint(x);
    u2 r = __builtin_amdgcn_permlane16_swap(xi, xi, false, false);
    x = __uint_as_float(r.x) + __uint_as_float(r.y);
    xi = __float_as_uint(x);
    r = __builtin_amdgcn_permlane32_swap(xi, xi, false, false);
    return __uint_as_float(r.x) + __uint_as_float(r.y);
  }
#else
  x += __shfl_xor(x, 16);
  x += __shfl_xor(x, 32);
  return x;
#endif
#else
  x += __shfl_xor(x, 16);
  x += __shfl_xor(x, 32);
  return x;
#endif
}

// One block (512 threads) per matrix. Thread (tx=tid&15, ty=tid>>4) owns
// rows [8*ty, 8*ty+8), cols [16*tx, 16*tx+16). V0 = exp(alpha/tau) is frozen
// in registers; only row scales R and col scales C evolve:
//   R_i = 1/sum_j V0[ij]*C_j ;  C_j = 1/sum_i V0[ij]*R_i
__global__ __launch_bounds__(512, 2) void sinkhorn16(const float* __restrict__ alpha,
                                                     float* __restrict__ out) {
  // k-major partial layout: partial for col 16*tx+4*k+m of wave w lives at
  // colpart[w*256 + k*64 + tx*4 + m]  -> all LDS phases conflict-free.
  __shared__ float colpart[8 * 256];
  __shared__ float colrcp[256];

  const int tid = threadIdx.x;
  const int tx  = tid & 15;
  const int ty  = tid >> 4;         // 0..31
  const int dq  = (tid >> 4) & 3;   // lane>>4
  const int wv  = tid >> 6;         // 0..7

  const size_t mbase = (size_t)blockIdx.x * (256 * 256);
  const float* A = alpha + mbase;
  float*       O = out + mbase;

  float v[8][16];

  // Load + exp(alpha/TAU); 1/0.1f is exactly 10.0f.
#pragma unroll
  for (int i = 0; i < 8; ++i) {
    const float4* src = (const float4*)(A + (size_t)(8 * ty + i) * 256 + 16 * tx);
#pragma unroll
    for (int k = 0; k < 4; ++k) {
      float4 x = src[k];
      v[i][4 * k + 0] = __expf(x.x * 10.0f);
      v[i][4 * k + 1] = __expf(x.y * 10.0f);
      v[i][4 * k + 2] = __expf(x.z * 10.0f);
      v[i][4 * k + 3] = __expf(x.w * 10.0f);
    }
  }

  float C[16], R[8];
#pragma unroll
  for (int j = 0; j < 16; ++j) C[j] = 1.0f;

  for (int it = 0; it < N_ITER; ++it) {
    // ---------- row phase: R_i = 1/sum_j V0[ij]*C_j  (no LDS) ----------
#pragma unroll
    for (int i = 0; i < 8; ++i) {
      float a0 = v[i][0] * C[0];
      float a1 = v[i][1] * C[1];
      float a2 = v[i][2] * C[2];
      float a3 = v[i][3] * C[3];
#pragma unroll
      for (int m = 1; m < 4; ++m) {
        a0 = fmaf(v[i][4 * m + 0], C[4 * m + 0], a0);
        a1 = fmaf(v[i][4 * m + 1], C[4 * m + 1], a1);
        a2 = fmaf(v[i][4 * m + 2], C[4 * m + 2], a2);
        a3 = fmaf(v[i][4 * m + 3], C[4 * m + 3], a3);
      }
      float s = row16_sum((a0 + a1) + (a2 + a3));
      R[i] = __builtin_amdgcn_rcpf(s);
    }

    // ---------- col phase: C_j = 1/sum_i V0[ij]*R_i ----------
    float p[16];
#pragma unroll
    for (int j = 0; j < 16; ++j) {
      float b0 = v[0][j] * R[0];
      float b1 = v[1][j] * R[1];
#pragma unroll
      for (int i = 1; i < 4; ++i) {
        b0 = fmaf(v[2 * i + 0][j], R[2 * i + 0], b0);
        b1 = fmaf(v[2 * i + 1][j], R[2 * i + 1], b1);
      }
      p[j] = dq4_sum(b0 + b1);  // sum over the wave's 4 row groups
    }

    if (dq == 0) {  // 16 lanes per wave write the wave's 256 col partials
      float* dst = &colpart[wv * 256 + tx * 4];
#pragma unroll
      for (int k = 0; k < 4; ++k)
        *((float4*)(dst + k * 64)) =
            make_float4(p[4 * k + 0], p[4 * k + 1], p[4 * k + 2], p[4 * k + 3]);
    }
    __syncthreads();

    if (tid < 256) {  // sum 8 wave-partials per col, reciprocal
      float c0 = colpart[0 * 256 + tid] + colpart[1 * 256 + tid];
      float c1 = colpart[2 * 256 + tid] + colpart[3 * 256 + tid];
      float c2 = colpart[4 * 256 + tid] + colpart[5 * 256 + tid];
      float c3 = colpart[6 * 256 + tid] + colpart[7 * 256 + tid];
      colrcp[tid] = __builtin_amdgcn_rcpf((c0 + c1) + (c2 + c3));
    }
    __syncthreads();

    // broadcast C back (same k-major addressing as the partial writes)
#pragma unroll
    for (int k = 0; k < 4; ++k) {
      float4 rc = *((const float4*)(&colrcp[k * 64 + tx * 4]));
      C[4 * k + 0] = rc.x;
      C[4 * k + 1] = rc.y;
      C[4 * k + 2] = rc.z;
      C[4 * k + 3] = rc.w;
    }
  }

  // ---------- epilogue: out = V0 * R_i * C_j ----------
#pragma unroll
  for (int i = 0; i < 8; ++i) {
    float4* dst = (float4*)(O + (size_t)(8 * ty + i) * 256 + 16 * tx);
#pragma unroll
    for (int k = 0; k < 4; ++k) {
      dst[k] = make_float4(v[i][4 * k + 0] * R[i] * C[4 * k + 0],
                           v[i][4 * k + 1] * R[i] * C[4 * k + 1],
                           v[i][4 * k + 2] * R[i] * C[4 * k + 2],
                           v[i][4 * k + 3] * R[i] * C[4 * k + 3]);
    }
  }
}

extern "C" void kernel_launch(void* const* d_in, const int* in_sizes, int n_in,
                              void* d_out, int out_size, void* d_ws, size_t ws_size,
                              hipStream_t stream) {
  const float* alpha = (const float*)d_in[0];
  float* out = (float*)d_out;
  sinkhorn16<<<dim3(16), dim3(512), 0, stream>>>(alpha, out);
}